// Round 1
// baseline (491.675 us; speedup 1.0000x reference)
//
#include <hip/hip_runtime.h>

// Depthwise 3x3 conv, stride 1, pad 1, NCHW fp32 + bias.
// N=16, C=256, H=W=128. Memory-bound: ~512 MiB min traffic -> ~85us floor.

constexpr int N_ = 16;
constexpr int C_ = 256;
constexpr int H_ = 128;
constexpr int W_ = 128;
constexpr int ROWS_PER_BLOCK = 8;                 // 256 threads = 32 lanes x 8 rows
constexpr int TILES_PER_PLANE = H_ / ROWS_PER_BLOCK;  // 16

__global__ __launch_bounds__(256) void dwconv3x3_kernel(
    const float* __restrict__ x,
    const float* __restrict__ weight,   // (C,1,3,3)
    const float* __restrict__ bias,     // (C,)
    float* __restrict__ out) {

    const int lane = threadIdx.x & 31;    // 32 lanes -> 128 cols (float4 each)
    const int ty   = threadIdx.x >> 5;    // 8 rows per block

    const int bid  = blockIdx.x;
    const int tile = bid & (TILES_PER_PLANE - 1);
    const int nc   = bid >> 4;            // n*C + c, uniform per block
    const int c    = nc & (C_ - 1);

    const int h  = tile * ROWS_PER_BLOCK + ty;
    const int w0 = lane * 4;

    const float* __restrict__ xp = x + (size_t)nc * (H_ * W_);
    float* __restrict__ op = out + (size_t)nc * (H_ * W_) + h * W_ + w0;

    // Channel-uniform weights/bias -> scalar loads (broadcast).
    const float* wp = weight + c * 9;
    const float w00 = wp[0], w01 = wp[1], w02 = wp[2];
    const float w10 = wp[3], w11 = wp[4], w12 = wp[5];
    const float w20 = wp[6], w21 = wp[7], w22 = wp[8];
    const float b = bias[c];

    // e[kr][0..5]: left scalar, 4-wide aligned float4, right scalar
    float e[3][6];
#pragma unroll
    for (int kr = 0; kr < 3; ++kr) {
        const int r = h + kr - 1;
        if (r < 0 || r >= H_) {
#pragma unroll
            for (int j = 0; j < 6; ++j) e[kr][j] = 0.0f;
        } else {
            const float4 v = *(const float4*)(xp + r * W_ + w0);
            e[kr][1] = v.x; e[kr][2] = v.y; e[kr][3] = v.z; e[kr][4] = v.w;
            e[kr][0] = (w0 > 0)       ? xp[r * W_ + w0 - 1] : 0.0f;
            e[kr][5] = (w0 + 4 < W_)  ? xp[r * W_ + w0 + 4] : 0.0f;
        }
    }

    float o[4];
#pragma unroll
    for (int j = 0; j < 4; ++j) {
        float s = b;
        s = fmaf(w00, e[0][j],     s);
        s = fmaf(w01, e[0][j + 1], s);
        s = fmaf(w02, e[0][j + 2], s);
        s = fmaf(w10, e[1][j],     s);
        s = fmaf(w11, e[1][j + 1], s);
        s = fmaf(w12, e[1][j + 2], s);
        s = fmaf(w20, e[2][j],     s);
        s = fmaf(w21, e[2][j + 1], s);
        s = fmaf(w22, e[2][j + 2], s);
        o[j] = s;
    }

    float4 ov;
    ov.x = o[0]; ov.y = o[1]; ov.z = o[2]; ov.w = o[3];
    *(float4*)op = ov;
}

extern "C" void kernel_launch(void* const* d_in, const int* in_sizes, int n_in,
                              void* d_out, int out_size, void* d_ws, size_t ws_size,
                              hipStream_t stream) {
    const float* x      = (const float*)d_in[0];
    const float* weight = (const float*)d_in[1];
    const float* bias   = (const float*)d_in[2];
    float* out          = (float*)d_out;

    const int grid = N_ * C_ * TILES_PER_PLANE;  // 65536 blocks
    dwconv3x3_kernel<<<grid, 256, 0, stream>>>(x, weight, bias, out);
}

// Round 2
// 432.994 us; speedup vs baseline: 1.1355x; 1.1355x over previous
//
#include <hip/hip_runtime.h>

// Depthwise 3x3 conv, stride 1, pad 1, NCHW fp32 + bias.
// N=16, C=256, H=W=128. Memory-bound: ~512 MiB min traffic -> ~69-85us floor.
//
// R1: 4 output rows per thread (6-row register window), halo columns via
// __shfl (width 32) instead of scalar gathers -> every vmem op is a fully
// coalesced float4; vmem insts per output byte cut 4x vs R0.

constexpr int N_ = 16;
constexpr int C_ = 256;
constexpr int H_ = 128;
constexpr int W_ = 128;
constexpr int ROWS_PER_THREAD = 4;
constexpr int TY_PER_BLOCK = 8;                         // 256 threads = 32 lanes x 8
constexpr int ROWS_PER_BLOCK = ROWS_PER_THREAD * TY_PER_BLOCK;   // 32
constexpr int TILES_PER_PLANE = H_ / ROWS_PER_BLOCK;    // 4

__global__ __launch_bounds__(256) void dwconv3x3_kernel(
    const float* __restrict__ x,
    const float* __restrict__ weight,   // (C,1,3,3)
    const float* __restrict__ bias,     // (C,)
    float* __restrict__ out) {

    const int lane = threadIdx.x & 31;    // 32 lanes -> 128 cols (float4 each)
    const int ty   = threadIdx.x >> 5;

    const int bid  = blockIdx.x;
    const int tile = bid & (TILES_PER_PLANE - 1);
    const int nc   = bid >> 2;            // n*C + c, uniform per block
    const int c    = nc & (C_ - 1);

    const int h0 = tile * ROWS_PER_BLOCK + ty * ROWS_PER_THREAD;  // first output row
    const int w0 = lane * 4;

    const float* __restrict__ xp = x + (size_t)nc * (H_ * W_);
    float* __restrict__ op = out + (size_t)nc * (H_ * W_);

    // Channel-uniform weights/bias -> scalar broadcast loads.
    const float* wp = weight + c * 9;
    float wgt[3][3];
#pragma unroll
    for (int k = 0; k < 3; ++k) {
#pragma unroll
        for (int j = 0; j < 3; ++j) wgt[k][j] = wp[k * 3 + j];
    }
    const float b = bias[c];

    // Issue all 6 input-row loads up front (independent, coalesced float4).
    float4 rows[6];
#pragma unroll
    for (int i = 0; i < 6; ++i) {
        const int r = h0 - 1 + i;
        if (r >= 0 && r < H_) {
            rows[i] = *(const float4*)(xp + r * W_ + w0);
        } else {
            rows[i] = make_float4(0.f, 0.f, 0.f, 0.f);
        }
    }

    float acc[ROWS_PER_THREAD][4];
#pragma unroll
    for (int o = 0; o < ROWS_PER_THREAD; ++o)
#pragma unroll
        for (int j = 0; j < 4; ++j) acc[o][j] = b;

    // Input row i (abs row h0-1+i) feeds output rows o = i-2..i with weight
    // row k = i - o. Column halo from neighbor lanes via shfl (width 32: one
    // subgroup == one full 128-wide image row).
#pragma unroll
    for (int i = 0; i < 6; ++i) {
        float e0 = __shfl_up(rows[i].w, 1, 32);
        if (lane == 0) e0 = 0.f;                 // image left edge
        float e5 = __shfl_down(rows[i].x, 1, 32);
        if (lane == 31) e5 = 0.f;                // image right edge
        const float e[6] = {e0, rows[i].x, rows[i].y, rows[i].z, rows[i].w, e5};

        const int olo = (i >= 2) ? (i - 2) : 0;
        const int ohi = (i < ROWS_PER_THREAD) ? i : (ROWS_PER_THREAD - 1);
#pragma unroll
        for (int o = olo; o <= ohi; ++o) {
            const int k = i - o;  // weight row, compile-time after unroll
#pragma unroll
            for (int j = 0; j < 4; ++j) {
                float s = acc[o][j];
                s = fmaf(wgt[k][0], e[j],     s);
                s = fmaf(wgt[k][1], e[j + 1], s);
                s = fmaf(wgt[k][2], e[j + 2], s);
                acc[o][j] = s;
            }
        }
    }

#pragma unroll
    for (int o = 0; o < ROWS_PER_THREAD; ++o) {
        float4 ov;
        ov.x = acc[o][0]; ov.y = acc[o][1]; ov.z = acc[o][2]; ov.w = acc[o][3];
        *(float4*)(op + (h0 + o) * W_ + w0) = ov;
    }
}

extern "C" void kernel_launch(void* const* d_in, const int* in_sizes, int n_in,
                              void* d_out, int out_size, void* d_ws, size_t ws_size,
                              hipStream_t stream) {
    const float* x      = (const float*)d_in[0];
    const float* weight = (const float*)d_in[1];
    const float* bias   = (const float*)d_in[2];
    float* out          = (float*)d_out;

    const int grid = N_ * C_ * TILES_PER_PLANE;  // 16384 blocks
    dwconv3x3_kernel<<<grid, 256, 0, stream>>>(x, weight, bias, out);
}